// Round 7
// baseline (222.180 us; speedup 1.0000x reference)
//
#include <hip/hip_runtime.h>

#define NB 32            // batch
#define NT 1024          // input time steps
#define ND 384           // feature dim
#define ND4 (ND / 4)     // 96 float4 per frame
#define THREADS 256
#define ILP 8
#define CHUNK (THREADS * ILP)   // 2048 float4 per block
#define MAXF 24                 // frames spanned by one chunk: ceil(2047/96)+1 = 23, +1 slack

typedef float vfloat4 __attribute__((ext_vector_type(4)));

// Single fused kernel. grid = (ceil(f4pb/CHUNK), NB).
// Phase 1: block redundantly scans its batch's durations row (4 KB, L2-hot)
//          into LDS csum — int4 load/thread, wave shuffle-scan, 4-wave combine.
// Phase 2: 24 threads binary-search LDS csum -> per-frame source table s_t.
// Phase 3: stream CHUNK float4s: enc gather via s_t (LDS), nontemporal store.
__global__ void __launch_bounds__(THREADS)
fused_kernel(const vfloat4* __restrict__ enc,
             const int* __restrict__ dur,
             vfloat4* __restrict__ out,
             int max_len, int f4_per_batch) {
    __shared__ int s_csum[NT];
    __shared__ int s_wsum[4];
    __shared__ int s_t[MAXF];

    const int b    = blockIdx.y;
    const int tid  = threadIdx.x;
    const int lane = tid & 63;
    const int w    = tid >> 6;              // 4 waves

    // --- Phase 1: inclusive scan of dur[b,:] into s_csum -------------------
    const int4 dv = ((const int4*)(dur + b * NT))[tid];   // 4 consecutive ints
    const int l0 = dv.x;
    const int l1 = l0 + dv.y;
    const int l2 = l1 + dv.z;
    const int l3 = l2 + dv.w;               // thread-local inclusive sums
    int x = l3;
    #pragma unroll
    for (int off = 1; off < 64; off <<= 1) {
        int y = __shfl_up(x, off, 64);
        if (lane >= off) x += y;
    }
    if (lane == 63) s_wsum[w] = x;
    __syncthreads();
    int base = x - l3;                       // exclusive prefix within wave
    #pragma unroll
    for (int i = 0; i < 3; ++i)
        if (w > i) base += s_wsum[i];        // add preceding waves
    s_csum[4 * tid + 0] = base + l0;
    s_csum[4 * tid + 1] = base + l1;
    s_csum[4 * tid + 2] = base + l2;
    s_csum[4 * tid + 3] = base + l3;
    __syncthreads();
    const int total = s_csum[NT - 1];

    // --- Phase 2: per-frame source index for this block's window -----------
    const int jbase = blockIdx.x * CHUNK;
    const int p0    = jbase / ND4;
    if (tid < MAXF) {
        const int p = p0 + tid;
        int res = 0;                         // pad region -> frame 0 (masked)
        if (p < total) {
            int lo = 0, hi = NT - 1;         // first t with csum[t] > p
            while (lo < hi) {
                const int mid = (lo + hi) >> 1;
                if (s_csum[mid] <= p) lo = mid + 1; else hi = mid;
            }
            res = lo;
        }
        s_t[tid] = res;
    }
    __syncthreads();

    // --- Phase 3: streaming copy -------------------------------------------
    const int total_f4 = total * ND4;
    const vfloat4* enc_b = enc + (size_t)b * NT * ND4;
    vfloat4* out_b = out + (size_t)b * (size_t)max_len * ND4;

    int j[ILP], tt[ILP], dd[ILP];
    #pragma unroll
    for (int k = 0; k < ILP; ++k) {
        j[k] = jbase + tid + k * THREADS;
        const int jc = j[k] < f4_per_batch ? j[k] : f4_per_batch - 1;
        const int p  = jc / ND4;             // const-divisor magic mul
        dd[k] = jc - p * ND4;
        tt[k] = s_t[p - p0];                 // LDS, no global round-trip
    }
    vfloat4 v[ILP];
    #pragma unroll
    for (int k = 0; k < ILP; ++k)
        v[k] = enc_b[(size_t)tt[k] * ND4 + dd[k]];   // independent gathers
    #pragma unroll
    for (int k = 0; k < ILP; ++k) {
        if (j[k] >= total_f4)
            v[k] = (vfloat4){0.f, 0.f, 0.f, 0.f};    // zero-pad region
        if (j[k] < f4_per_batch)
            __builtin_nontemporal_store(v[k], &out_b[j[k]]);
    }
}

extern "C" void kernel_launch(void* const* d_in, const int* in_sizes, int n_in,
                              void* d_out, int out_size, void* d_ws, size_t ws_size,
                              hipStream_t stream) {
    const float* enc = (const float*)d_in[0];
    const int*   dur = (const int*)d_in[1];
    float* out = (float*)d_out;

    const int max_len = out_size / (NB * ND);   // out_size = NB*max_len*ND
    const int f4pb = max_len * ND4;
    const int blocks_x = (f4pb + CHUNK - 1) / CHUNK;
    dim3 grid(blocks_x, NB);
    fused_kernel<<<grid, THREADS, 0, stream>>>(
        (const vfloat4*)enc, dur, (vfloat4*)out, max_len, f4pb);
}